// Round 1
// baseline (786.425 us; speedup 1.0000x reference)
//
#include <hip/hip_runtime.h>
#include <math.h>

#define B 8
#define P 512
#define C 1024
#define H 8
#define WD 64
#define BN_EPS 1e-5f

// ---------------------------------------------------------------------------
// Kernel 1: Y[b,d,p] = BN( sum_c W[d,c] * x[b,p,c] )   (Y in (B,C,P) layout)
// 64x64 output tile per block, K-chunk 32, 256 threads, 4x4 micro-tile.
// ---------------------------------------------------------------------------
__global__ __launch_bounds__(256) void qkv_bn_kernel(
    const float* __restrict__ x, const float* __restrict__ Wq,
    const float* __restrict__ gamma, const float* __restrict__ beta,
    const float* __restrict__ mean, const float* __restrict__ var,
    float* __restrict__ Y)
{
    const int dt = blockIdx.x;   // 16 d-tiles
    const int pt = blockIdx.y;   // 8 p-tiles
    const int b  = blockIdx.z;   // 8
    const int d0 = dt * 64, p0 = pt * 64;

    __shared__ float Wt[64][33];
    __shared__ float Xt[64][33];

    const int t = threadIdx.x;
    const int ty = t >> 4, tx = t & 15;

    float acc[4][4] = {};

    for (int c0 = 0; c0 < C; c0 += 32) {
        #pragma unroll
        for (int i = 0; i < 8; ++i) {
            int idx = t + i * 256;
            int r = idx >> 5, k = idx & 31;
            Wt[r][k] = Wq[(size_t)(d0 + r) * C + c0 + k];
            Xt[r][k] = x[((size_t)b * P + p0 + r) * C + c0 + k];
        }
        __syncthreads();
        #pragma unroll
        for (int kk = 0; kk < 32; ++kk) {
            float wa[4], xa[4];
            #pragma unroll
            for (int i = 0; i < 4; ++i) wa[i] = Wt[ty * 4 + i][kk];
            #pragma unroll
            for (int j = 0; j < 4; ++j) xa[j] = Xt[tx * 4 + j][kk];
            #pragma unroll
            for (int i = 0; i < 4; ++i)
                #pragma unroll
                for (int j = 0; j < 4; ++j)
                    acc[i][j] += wa[i] * xa[j];
        }
        __syncthreads();
    }

    #pragma unroll
    for (int i = 0; i < 4; ++i) {
        int d = d0 + ty * 4 + i;
        float sc = rsqrtf(var[d] + BN_EPS) * gamma[d];
        float mu = mean[d], bt = beta[d];
        #pragma unroll
        for (int j = 0; j < 4; ++j) {
            int p = p0 + tx * 4 + j;
            Y[((size_t)b * C + d) * P + p] = (acc[i][j] - mu) * sc + bt;
        }
    }
}

// ---------------------------------------------------------------------------
// Kernel 2: scores[b,h,c,d] = (1/gs) * sum_w Y[b,c,h*64+w] * Y[b,d,h*64+w]
// Written raw into the attn region of d_out; softmax-ed in-place by kernel 3.
// ---------------------------------------------------------------------------
__global__ __launch_bounds__(256) void scores_kernel(
    const float* __restrict__ Y, const float* __restrict__ gs_ptr,
    float* __restrict__ attn)
{
    const int ct = blockIdx.x;   // 16
    const int dt = blockIdx.y;   // 16
    const int bh = blockIdx.z;   // 64  (b*H + h)
    const int b = bh >> 3, h = bh & 7;
    const float scale = 1.0f / gs_ptr[0];

    __shared__ float Qc[64][65];
    __shared__ float Qd[64][65];

    const int t = threadIdx.x;
    const int ty = t >> 4, tx = t & 15;

    const float* Yb = Y + (size_t)b * C * P + h * WD;

    #pragma unroll
    for (int i = 0; i < 16; ++i) {
        int idx = t + i * 256;
        int r = idx >> 6, k = idx & 63;
        Qc[r][k] = Yb[(size_t)(ct * 64 + r) * P + k];
        Qd[r][k] = Yb[(size_t)(dt * 64 + r) * P + k];
    }
    __syncthreads();

    float acc[4][4] = {};
    #pragma unroll
    for (int kk = 0; kk < 64; ++kk) {
        float qa[4], qb[4];
        #pragma unroll
        for (int i = 0; i < 4; ++i) qa[i] = Qc[ty * 4 + i][kk];
        #pragma unroll
        for (int j = 0; j < 4; ++j) qb[j] = Qd[tx * 4 + j][kk];
        #pragma unroll
        for (int i = 0; i < 4; ++i)
            #pragma unroll
            for (int j = 0; j < 4; ++j)
                acc[i][j] += qa[i] * qb[j];
    }

    float* out = attn + ((size_t)bh * C + ct * 64) * C + dt * 64;
    #pragma unroll
    for (int i = 0; i < 4; ++i)
        #pragma unroll
        for (int j = 0; j < 4; ++j)
            out[(size_t)(ty * 4 + i) * C + tx * 4 + j] = acc[i][j] * scale;
}

// ---------------------------------------------------------------------------
// Kernel 3: in-place softmax over the H axis: attn[b,:,c,d] = softmax(scores)
// Each thread owns one (b,c,d) triple -> 8 strided values.
// ---------------------------------------------------------------------------
__global__ __launch_bounds__(256) void softmax_h_kernel(float* __restrict__ attn)
{
    const size_t hs = (size_t)C * C;          // stride between heads
    const size_t n = (size_t)B * C * C;       // (b,c,d) triples
    for (size_t idx = (size_t)blockIdx.x * 256 + threadIdx.x; idx < n;
         idx += (size_t)gridDim.x * 256) {
        size_t b = idx / hs;
        size_t cd = idx - b * hs;
        float* p = attn + b * H * hs + cd;
        float v[H];
        float m = -1e30f;
        #pragma unroll
        for (int h = 0; h < H; ++h) { v[h] = p[h * hs]; m = fmaxf(m, v[h]); }
        float s = 0.0f;
        #pragma unroll
        for (int h = 0; h < H; ++h) { v[h] = __expf(v[h] - m); s += v[h]; }
        float inv = 1.0f / s;
        #pragma unroll
        for (int h = 0; h < H; ++h) p[h * hs] = v[h] * inv;
    }
}

// ---------------------------------------------------------------------------
// Kernel 4: out0[b, h*64+w, c] = sum_d attn[b,h,c,d] * Y[b,d,h*64+w]
// Tile: 64 w x 64 c per block; K over d in chunks of 64.
// ---------------------------------------------------------------------------
__global__ __launch_bounds__(256) void pv_kernel(
    const float* __restrict__ attn, const float* __restrict__ Y,
    float* __restrict__ out0)
{
    const int ct = blockIdx.x;   // 16 c-tiles
    const int bh = blockIdx.y;   // 64
    const int b = bh >> 3, h = bh & 7;

    __shared__ float At[64][65];   // [c within tile][d within chunk]
    __shared__ float Vt[64][65];   // [d within chunk][w]

    const int t = threadIdx.x;
    const int ty = t >> 4, tx = t & 15;

    const float* Ab = attn + ((size_t)bh * C + ct * 64) * C;
    const float* Yb = Y + (size_t)b * C * P + h * WD;

    float acc[4][4] = {};   // [i: w][j: c]

    for (int d0 = 0; d0 < C; d0 += 64) {
        #pragma unroll
        for (int i = 0; i < 16; ++i) {
            int idx = t + i * 256;
            int r = idx >> 6, k = idx & 63;
            At[r][k] = Ab[(size_t)r * C + d0 + k];
            Vt[r][k] = Yb[(size_t)(d0 + r) * P + k];
        }
        __syncthreads();
        #pragma unroll
        for (int kk = 0; kk < 64; ++kk) {
            float va[4], aa[4];
            #pragma unroll
            for (int i = 0; i < 4; ++i) va[i] = Vt[kk][ty * 4 + i];
            #pragma unroll
            for (int j = 0; j < 4; ++j) aa[j] = At[tx * 4 + j][kk];
            #pragma unroll
            for (int i = 0; i < 4; ++i)
                #pragma unroll
                for (int j = 0; j < 4; ++j)
                    acc[i][j] += va[i] * aa[j];
        }
        __syncthreads();
    }

    // w = ty*4+i, c = ct*64 + tx*4+j
    float* ob = out0 + ((size_t)b * P + h * WD) * C + (size_t)ct * 64;
    #pragma unroll
    for (int i = 0; i < 4; ++i) {
        int w = ty * 4 + i;
        #pragma unroll
        for (int j = 0; j < 4; ++j)
            ob[(size_t)w * C + tx * 4 + j] = acc[i][j];
    }
}

extern "C" void kernel_launch(void* const* d_in, const int* in_sizes, int n_in,
                              void* d_out, int out_size, void* d_ws, size_t ws_size,
                              hipStream_t stream) {
    const float* x     = (const float*)d_in[0];
    const float* Wq    = (const float*)d_in[1];
    const float* gamma = (const float*)d_in[2];
    const float* beta  = (const float*)d_in[3];
    const float* mean  = (const float*)d_in[4];
    const float* var   = (const float*)d_in[5];
    const float* gs    = (const float*)d_in[6];

    float* out0 = (float*)d_out;                          // h: (B,P,C)
    float* attn = (float*)d_out + (size_t)B * P * C;      // attn: (B,H,C,C)
    float* Y    = (float*)d_ws;                           // (B,C,P) = 16 MB

    qkv_bn_kernel<<<dim3(16, 8, 8), 256, 0, stream>>>(x, Wq, gamma, beta, mean, var, Y);
    scores_kernel<<<dim3(16, 16, 64), 256, 0, stream>>>(Y, gs, attn);
    softmax_h_kernel<<<2048, 256, 0, stream>>>(attn);
    pv_kernel<<<dim3(16, 64), 256, 0, stream>>>(attn, Y, out0);
}

// Round 2
// 519.235 us; speedup vs baseline: 1.5146x; 1.5146x over previous
//
#include <hip/hip_runtime.h>
#include <math.h>

#define B 8
#define P 512
#define C 1024
#define H 8
#define WD 64
#define BN_EPS 1e-5f

// ---------------------------------------------------------------------------
// Kernel 1: Y[b,d,p] = BN( sum_c W[d,c] * x[b,p,c] )   (Y in (B,C,P) layout)
// Tile: d=128 x p=64, 256 threads, micro 8(d)x4(p), K-chunk 32.
// LDS transposed [k][row], odd pitch -> conflict-free b32 reads/writes.
// ---------------------------------------------------------------------------
__global__ __launch_bounds__(256) void qkv_bn_kernel(
    const float* __restrict__ x, const float* __restrict__ Wq,
    const float* __restrict__ gamma, const float* __restrict__ beta,
    const float* __restrict__ mean, const float* __restrict__ var,
    float* __restrict__ Y)
{
    const int d0 = blockIdx.x * 128;   // 8 tiles
    const int p0 = blockIdx.y * 64;    // 8 tiles
    const int b  = blockIdx.z;         // 8

    __shared__ float Wt[32][129];      // [k][d]  (128 wide, pitch 129)
    __shared__ float Xt[32][65];       // [k][p]  (64 wide, pitch 65)

    const int t  = threadIdx.x;
    const int dx = t & 15;             // c-of-d index (16)
    const int py = t >> 4;             // p index (16)

    float acc[8][4] = {};              // [jd: g*4+q over d][jp over p]

    for (int c0 = 0; c0 < C; c0 += 32) {
        // stage W: 128 rows x 32 k
        #pragma unroll
        for (int i = 0; i < 4; ++i) {
            int fi = t + i * 256;              // 0..1023
            int r = fi >> 3, kb = fi & 7;      // r: d-row, kb: k block
            float4 v = *(const float4*)&Wq[(size_t)(d0 + r) * C + c0 + kb * 4];
            Wt[kb * 4 + 0][r] = v.x; Wt[kb * 4 + 1][r] = v.y;
            Wt[kb * 4 + 2][r] = v.z; Wt[kb * 4 + 3][r] = v.w;
        }
        // stage X: 64 rows x 32 k
        #pragma unroll
        for (int i = 0; i < 2; ++i) {
            int fi = t + i * 256;              // 0..511
            int r = fi >> 3, kb = fi & 7;      // r: p-row
            float4 v = *(const float4*)&x[((size_t)b * P + p0 + r) * C + c0 + kb * 4];
            Xt[kb * 4 + 0][r] = v.x; Xt[kb * 4 + 1][r] = v.y;
            Xt[kb * 4 + 2][r] = v.z; Xt[kb * 4 + 3][r] = v.w;
        }
        __syncthreads();
        #pragma unroll
        for (int kk = 0; kk < 32; ++kk) {
            float wa[8], xa[4];
            #pragma unroll
            for (int g = 0; g < 2; ++g)
                #pragma unroll
                for (int q = 0; q < 4; ++q)
                    wa[g * 4 + q] = Wt[kk][g * 64 + dx * 4 + q];
            #pragma unroll
            for (int j = 0; j < 4; ++j) xa[j] = Xt[kk][py * 4 + j];
            #pragma unroll
            for (int jd = 0; jd < 8; ++jd)
                #pragma unroll
                for (int j = 0; j < 4; ++j)
                    acc[jd][j] += wa[jd] * xa[j];
        }
        __syncthreads();
    }

    #pragma unroll
    for (int jd = 0; jd < 8; ++jd) {
        int d = d0 + (jd >> 2) * 64 + dx * 4 + (jd & 3);
        float sc = rsqrtf(var[d] + BN_EPS) * gamma[d];
        float mu = mean[d], bt = beta[d];
        float4 v;
        v.x = (acc[jd][0] - mu) * sc + bt;
        v.y = (acc[jd][1] - mu) * sc + bt;
        v.z = (acc[jd][2] - mu) * sc + bt;
        v.w = (acc[jd][3] - mu) * sc + bt;
        *(float4*)&Y[((size_t)b * C + d) * P + p0 + py * 4] = v;
    }
}

// ---------------------------------------------------------------------------
// Kernel 2: fused scores + head-softmax.
// Block owns (b, c-tile 64, d-tile 64); computes scores for ALL 8 heads
// (acc[8][4][4] in regs), softmaxes over h in-register, writes attn once.
// ---------------------------------------------------------------------------
__global__ __launch_bounds__(256) void scores_softmax_kernel(
    const float* __restrict__ Y, const float* __restrict__ gs_ptr,
    float* __restrict__ attn)
{
    const int ct = blockIdx.x;   // 16
    const int dt = blockIdx.y;   // 16
    const int b  = blockIdx.z;   // 8
    const float scale = 1.0f / gs_ptr[0];

    __shared__ float Qc[64][65];   // [w][c-row]
    __shared__ float Qd[64][65];   // [w][d-row]

    const int t  = threadIdx.x;
    const int ty = t >> 4, tx = t & 15;

    const float* Yc = Y + (size_t)b * C * P + (size_t)ct * 64 * P;
    const float* Yd = Y + (size_t)b * C * P + (size_t)dt * 64 * P;

    float acc[8][4][4] = {};

    #pragma unroll
    for (int h = 0; h < H; ++h) {
        #pragma unroll
        for (int i = 0; i < 4; ++i) {
            int fi = t + i * 256;          // 0..1023
            int r = fi >> 4, wb = fi & 15; // r: row, wb: w block
            float4 vc = *(const float4*)&Yc[(size_t)r * P + h * 64 + wb * 4];
            float4 vd = *(const float4*)&Yd[(size_t)r * P + h * 64 + wb * 4];
            Qc[wb * 4 + 0][r] = vc.x; Qc[wb * 4 + 1][r] = vc.y;
            Qc[wb * 4 + 2][r] = vc.z; Qc[wb * 4 + 3][r] = vc.w;
            Qd[wb * 4 + 0][r] = vd.x; Qd[wb * 4 + 1][r] = vd.y;
            Qd[wb * 4 + 2][r] = vd.z; Qd[wb * 4 + 3][r] = vd.w;
        }
        __syncthreads();
        #pragma unroll 8
        for (int kk = 0; kk < 64; ++kk) {
            float qa[4], qb[4];
            #pragma unroll
            for (int i = 0; i < 4; ++i) qa[i] = Qc[kk][ty * 4 + i];
            #pragma unroll
            for (int j = 0; j < 4; ++j) qb[j] = Qd[kk][tx * 4 + j];
            #pragma unroll
            for (int i = 0; i < 4; ++i)
                #pragma unroll
                for (int j = 0; j < 4; ++j)
                    acc[h][i][j] += qa[i] * qb[j];
        }
        __syncthreads();
    }

    // in-register softmax over h per (c,d) element, then write all 8 planes
    #pragma unroll
    for (int i = 0; i < 4; ++i) {
        #pragma unroll
        for (int j = 0; j < 4; ++j) {
            float m = -1e30f;
            #pragma unroll
            for (int h = 0; h < H; ++h) {
                acc[h][i][j] *= scale;
                m = fmaxf(m, acc[h][i][j]);
            }
            float s = 0.0f;
            #pragma unroll
            for (int h = 0; h < H; ++h) {
                acc[h][i][j] = __expf(acc[h][i][j] - m);
                s += acc[h][i][j];
            }
            float inv = 1.0f / s;
            #pragma unroll
            for (int h = 0; h < H; ++h) acc[h][i][j] *= inv;
        }
    }

    const size_t hs = (size_t)C * C;
    float* outb = attn + (size_t)b * H * hs + ((size_t)ct * 64) * C + dt * 64;
    #pragma unroll
    for (int h = 0; h < H; ++h) {
        #pragma unroll
        for (int i = 0; i < 4; ++i) {
            float4 v = make_float4(acc[h][i][0], acc[h][i][1],
                                   acc[h][i][2], acc[h][i][3]);
            *(float4*)&outb[h * hs + (size_t)(ty * 4 + i) * C + tx * 4] = v;
        }
    }
}

// ---------------------------------------------------------------------------
// Kernel 3: out0[b, h*64+w, c] = sum_d attn[b,h,c,d] * Y[b,d,h*64+w]
// Tile: c=128 x w=64 per block, micro 8(c)x4(w), K-chunk 64 over d.
// ---------------------------------------------------------------------------
__global__ __launch_bounds__(256) void pv_kernel(
    const float* __restrict__ attn, const float* __restrict__ Y,
    float* __restrict__ out0)
{
    const int ct = blockIdx.x;   // 8 c-tiles of 128
    const int bh = blockIdx.y;   // 64
    const int b = bh >> 3, h = bh & 7;

    __shared__ float At[64][129];  // [d][c]  (128 wide)
    __shared__ float Vt[64][65];   // [d][w]

    const int t  = threadIdx.x;
    const int cx = t & 15;         // c index (16)
    const int wy = t >> 4;         // w index (16)

    const float* Ab = attn + ((size_t)bh * C + (size_t)ct * 128) * C;
    const float* Yb = Y + (size_t)b * C * P + h * WD;

    float acc[8][4] = {};          // [jc: g*4+q over c][jw over w]

    for (int d0 = 0; d0 < C; d0 += 64) {
        // stage At: 128 c-rows x 64 d, transposed
        #pragma unroll
        for (int i = 0; i < 8; ++i) {
            int fi = t + i * 256;               // 0..2047
            int r = fi >> 4, db = fi & 15;      // r: c-row, db: d block
            float4 v = *(const float4*)&Ab[(size_t)r * C + d0 + db * 4];
            At[db * 4 + 0][r] = v.x; At[db * 4 + 1][r] = v.y;
            At[db * 4 + 2][r] = v.z; At[db * 4 + 3][r] = v.w;
        }
        // stage Vt: 64 d-rows x 64 w, natural
        #pragma unroll
        for (int i = 0; i < 4; ++i) {
            int fi = t + i * 256;               // 0..1023
            int r = fi >> 4, wb = fi & 15;      // r: d-row, wb: w block
            float4 v = *(const float4*)&Yb[(size_t)(d0 + r) * P + wb * 4];
            Vt[r][wb * 4 + 0] = v.x; Vt[r][wb * 4 + 1] = v.y;
            Vt[r][wb * 4 + 2] = v.z; Vt[r][wb * 4 + 3] = v.w;
        }
        __syncthreads();
        #pragma unroll 8
        for (int kk = 0; kk < 64; ++kk) {
            float ca[8], wa[4];
            #pragma unroll
            for (int g = 0; g < 2; ++g)
                #pragma unroll
                for (int q = 0; q < 4; ++q)
                    ca[g * 4 + q] = At[kk][g * 64 + cx * 4 + q];
            #pragma unroll
            for (int jw = 0; jw < 4; ++jw) wa[jw] = Vt[kk][wy * 4 + jw];
            #pragma unroll
            for (int jc = 0; jc < 8; ++jc)
                #pragma unroll
                for (int jw = 0; jw < 4; ++jw)
                    acc[jc][jw] += ca[jc] * wa[jw];
        }
        __syncthreads();
    }

    // store: w = wy*4+jw, c = ct*128 + g*64 + cx*4+q
    #pragma unroll
    for (int jw = 0; jw < 4; ++jw) {
        size_t row = ((size_t)b * P + h * WD + wy * 4 + jw) * C + (size_t)ct * 128;
        #pragma unroll
        for (int g = 0; g < 2; ++g) {
            float4 v = make_float4(acc[g * 4 + 0][jw], acc[g * 4 + 1][jw],
                                   acc[g * 4 + 2][jw], acc[g * 4 + 3][jw]);
            *(float4*)&out0[row + g * 64 + cx * 4] = v;
        }
    }
}

extern "C" void kernel_launch(void* const* d_in, const int* in_sizes, int n_in,
                              void* d_out, int out_size, void* d_ws, size_t ws_size,
                              hipStream_t stream) {
    const float* x     = (const float*)d_in[0];
    const float* Wq    = (const float*)d_in[1];
    const float* gamma = (const float*)d_in[2];
    const float* beta  = (const float*)d_in[3];
    const float* mean  = (const float*)d_in[4];
    const float* var   = (const float*)d_in[5];
    const float* gs    = (const float*)d_in[6];

    float* out0 = (float*)d_out;                          // h: (B,P,C)
    float* attn = (float*)d_out + (size_t)B * P * C;      // attn: (B,H,C,C)
    float* Y    = (float*)d_ws;                           // (B,C,P) = 16 MB

    qkv_bn_kernel<<<dim3(8, 8, 8), 256, 0, stream>>>(x, Wq, gamma, beta, mean, var, Y);
    scores_softmax_kernel<<<dim3(16, 16, 8), 256, 0, stream>>>(Y, gs, attn);
    pv_kernel<<<dim3(8, 64), 256, 0, stream>>>(attn, Y, out0);
}

// Round 3
// 429.944 us; speedup vs baseline: 1.8291x; 1.2077x over previous
//
#include <hip/hip_runtime.h>
#include <math.h>

#define B 8
#define P 512
#define C 1024
#define H 8
#define WD 64
#define BN_EPS 1e-5f

typedef __attribute__((ext_vector_type(8))) __bf16 bf16x8;
typedef __attribute__((ext_vector_type(4))) __bf16 bf16x4;
typedef __attribute__((ext_vector_type(4))) float f32x4;

// ---------------------------------------------------------------------------
// Kernel 1: f32 GEMM + BN (as round 2), epilogue emits:
//   Yhi/Ylo: (B,C,P) bf16 hi/lo split   (for scores fragments)
//   Zhi:     (B,P,C) bf16 hi            (for pv V fragments, LDS-transposed)
// ---------------------------------------------------------------------------
__global__ __launch_bounds__(256) void qkv_bn_kernel(
    const float* __restrict__ x, const float* __restrict__ Wq,
    const float* __restrict__ gamma, const float* __restrict__ beta,
    const float* __restrict__ mean, const float* __restrict__ var,
    __bf16* __restrict__ Yhi, __bf16* __restrict__ Ylo, __bf16* __restrict__ Zhi)
{
    const int d0 = blockIdx.x * 128;   // 8 tiles
    const int p0 = blockIdx.y * 64;    // 8 tiles
    const int b  = blockIdx.z;         // 8

    __shared__ __align__(16) char smem[24832];
    float (*Wt)[129] = (float(*)[129])smem;                 // [k][d] 32x128
    float (*Xt)[65]  = (float(*)[65])(smem + 16512);        // [k][p] 32x64
    __bf16 (*tb)[136] = (__bf16(*)[136])smem;               // [p][d] 64x128 (reuse)

    const int t  = threadIdx.x;
    const int dx = t & 15;
    const int py = t >> 4;

    float acc[8][4] = {};

    for (int c0 = 0; c0 < C; c0 += 32) {
        #pragma unroll
        for (int i = 0; i < 4; ++i) {
            int fi = t + i * 256;
            int r = fi >> 3, kb = fi & 7;
            float4 v = *(const float4*)&Wq[(size_t)(d0 + r) * C + c0 + kb * 4];
            Wt[kb * 4 + 0][r] = v.x; Wt[kb * 4 + 1][r] = v.y;
            Wt[kb * 4 + 2][r] = v.z; Wt[kb * 4 + 3][r] = v.w;
        }
        #pragma unroll
        for (int i = 0; i < 2; ++i) {
            int fi = t + i * 256;
            int r = fi >> 3, kb = fi & 7;
            float4 v = *(const float4*)&x[((size_t)b * P + p0 + r) * C + c0 + kb * 4];
            Xt[kb * 4 + 0][r] = v.x; Xt[kb * 4 + 1][r] = v.y;
            Xt[kb * 4 + 2][r] = v.z; Xt[kb * 4 + 3][r] = v.w;
        }
        __syncthreads();
        #pragma unroll
        for (int kk = 0; kk < 32; ++kk) {
            float wa[8], xa[4];
            #pragma unroll
            for (int g = 0; g < 2; ++g)
                #pragma unroll
                for (int q = 0; q < 4; ++q)
                    wa[g * 4 + q] = Wt[kk][g * 64 + dx * 4 + q];
            #pragma unroll
            for (int j = 0; j < 4; ++j) xa[j] = Xt[kk][py * 4 + j];
            #pragma unroll
            for (int jd = 0; jd < 8; ++jd)
                #pragma unroll
                for (int j = 0; j < 4; ++j)
                    acc[jd][j] += wa[jd] * xa[j];
        }
        __syncthreads();
    }

    // ---- epilogue: BN, hi/lo split, direct Yhi/Ylo stores ----
    __bf16 hv[8][4];
    #pragma unroll
    for (int jd = 0; jd < 8; ++jd) {
        int d = d0 + (jd >> 2) * 64 + dx * 4 + (jd & 3);
        float sc = rsqrtf(var[d] + BN_EPS) * gamma[d];
        float mu = mean[d], bt = beta[d];
        bf16x4 hq, lq;
        #pragma unroll
        for (int j = 0; j < 4; ++j) {
            float n = (acc[jd][j] - mu) * sc + bt;
            __bf16 hb = (__bf16)n;
            __bf16 lb = (__bf16)(n - (float)hb);
            hv[jd][j] = hb;
            hq[j] = hb; lq[j] = lb;
        }
        size_t yi = ((size_t)b * C + d) * P + p0 + py * 4;
        *(bf16x4*)&Yhi[yi] = hq;
        *(bf16x4*)&Ylo[yi] = lq;
    }

    // ---- LDS transpose -> Zhi (B,P,C) ----
    #pragma unroll
    for (int jd = 0; jd < 8; ++jd) {
        int dl = (jd >> 2) * 64 + dx * 4 + (jd & 3);
        #pragma unroll
        for (int j = 0; j < 4; ++j)
            tb[py * 4 + j][dl] = hv[jd][j];
    }
    __syncthreads();
    {
        int pl = t >> 2, dsg = (t & 3) * 32;
        size_t zi = ((size_t)b * P + p0 + pl) * C + d0 + dsg;
        #pragma unroll
        for (int q = 0; q < 4; ++q) {
            bf16x8 v = *(const bf16x8*)&tb[pl][dsg + q * 8];
            *(bf16x8*)&Zhi[zi + q * 8] = v;
        }
    }
}

// ---------------------------------------------------------------------------
// Kernel 2: scores + head-softmax via split-bf16 MFMA, fragments from global.
// Block (b, ct, dt): 4 waves, each a 32x32 quadrant x 8 heads. No LDS/syncs.
// scores = Qhi*Qhi' + Qhi*Qlo' + Qlo*Qhi'  (lo*lo dropped, ~2^-18 rel err)
// ---------------------------------------------------------------------------
__global__ __launch_bounds__(256) void scores_softmax_mfma(
    const __bf16* __restrict__ Yhi, const __bf16* __restrict__ Ylo,
    const float* __restrict__ gs_ptr, float* __restrict__ attn)
{
    const int ct = blockIdx.x, dt = blockIdx.y, b = blockIdx.z;
    const int t = threadIdx.x, lane = t & 63, wid = t >> 6;
    const int quadc = (wid >> 1) * 32, quadd = (wid & 1) * 32;
    const int lr = lane & 15, lk = (lane >> 4) * 8;
    const float scale = 1.0f / gs_ptr[0];

    const size_t rowc = (size_t)b * C + ct * 64 + quadc + lr;
    const size_t rowd = (size_t)b * C + dt * 64 + quadd + lr;

    f32x4 acc[8][2][2];
    #pragma unroll
    for (int h = 0; h < H; ++h)
        #pragma unroll
        for (int tm = 0; tm < 2; ++tm)
            #pragma unroll
            for (int tn = 0; tn < 2; ++tn)
                acc[h][tm][tn] = (f32x4){0.f, 0.f, 0.f, 0.f};

    #pragma unroll
    for (int h = 0; h < H; ++h) {
        #pragma unroll
        for (int s = 0; s < 2; ++s) {
            const int col = h * 64 + s * 32 + lk;
            bf16x8 ah[2], al[2], bh[2], bl[2];
            #pragma unroll
            for (int tm = 0; tm < 2; ++tm) {
                size_t ia = (rowc + tm * 16) * P + col;
                ah[tm] = *(const bf16x8*)&Yhi[ia];
                al[tm] = *(const bf16x8*)&Ylo[ia];
                size_t ib = (rowd + tm * 16) * P + col;
                bh[tm] = *(const bf16x8*)&Yhi[ib];
                bl[tm] = *(const bf16x8*)&Ylo[ib];
            }
            #pragma unroll
            for (int tm = 0; tm < 2; ++tm)
                #pragma unroll
                for (int tn = 0; tn < 2; ++tn) {
                    acc[h][tm][tn] = __builtin_amdgcn_mfma_f32_16x16x32_bf16(ah[tm], bh[tn], acc[h][tm][tn], 0, 0, 0);
                    acc[h][tm][tn] = __builtin_amdgcn_mfma_f32_16x16x32_bf16(ah[tm], bl[tn], acc[h][tm][tn], 0, 0, 0);
                    acc[h][tm][tn] = __builtin_amdgcn_mfma_f32_16x16x32_bf16(al[tm], bh[tn], acc[h][tm][tn], 0, 0, 0);
                }
        }
    }

    // in-register softmax over h per (c,d) element
    #pragma unroll
    for (int tm = 0; tm < 2; ++tm)
        #pragma unroll
        for (int tn = 0; tn < 2; ++tn)
            #pragma unroll
            for (int r = 0; r < 4; ++r) {
                float v[8];
                float m = -1e30f;
                #pragma unroll
                for (int h = 0; h < H; ++h) {
                    v[h] = acc[h][tm][tn][r] * scale;
                    m = fmaxf(m, v[h]);
                }
                float ssum = 0.f;
                #pragma unroll
                for (int h = 0; h < H; ++h) { v[h] = __expf(v[h] - m); ssum += v[h]; }
                float inv = 1.0f / ssum;
                #pragma unroll
                for (int h = 0; h < H; ++h) acc[h][tm][tn][r] = v[h] * inv;
            }

    // write attn: C-frag layout col = lane&15 (d), row = (lane>>4)*4 + r (c)
    #pragma unroll
    for (int h = 0; h < H; ++h) {
        #pragma unroll
        for (int tm = 0; tm < 2; ++tm) {
            const int c = ct * 64 + quadc + tm * 16 + (lane >> 4) * 4;
            #pragma unroll
            for (int tn = 0; tn < 2; ++tn) {
                const int d = dt * 64 + quadd + tn * 16 + lr;
                float* op = attn + (((size_t)(b * H + h) * C + c) * C + d);
                #pragma unroll
                for (int r = 0; r < 4; ++r) op[(size_t)r * C] = acc[h][tm][tn][r];
            }
        }
    }
}

// ---------------------------------------------------------------------------
// Kernel 3: out0[b, h*64+w, c] = sum_d attn[b,h,c,d] * V[d,w]
// attn staged to LDS as hi/lo bf16 (XOR-swizzled rows); V frags from Zhi.
// Block (ct: 128 c, bh): 4 waves = 2(c-halves) x 2(w-halves of 32).
// ---------------------------------------------------------------------------
__global__ __launch_bounds__(256) void pv_mfma(
    const float* __restrict__ attn, const __bf16* __restrict__ Zhi,
    float* __restrict__ out0)
{
    const int ct = blockIdx.x;           // 8 tiles of 128 c
    const int bh = blockIdx.y;           // 64
    const int b = bh >> 3, h = bh & 7;
    const int t = threadIdx.x, lane = t & 63, wid = t >> 6;
    const int quadc = (wid >> 1) * 64;
    const int quadw = (wid & 1) * 32;
    const int lr = lane & 15, lk = (lane >> 4) * 8;

    __shared__ __bf16 Ah[128 * 64];
    __shared__ __bf16 Al[128 * 64];

    const float* Ab = attn + ((size_t)bh * C + (size_t)ct * 128) * C;

    f32x4 acc[4][2];
    #pragma unroll
    for (int tm = 0; tm < 4; ++tm)
        #pragma unroll
        for (int tn = 0; tn < 2; ++tn)
            acc[tm][tn] = (f32x4){0.f, 0.f, 0.f, 0.f};

    const int sr  = t >> 4;        // 0..15 staging row base
    const int scb = (t & 15) * 4;  // staging col

    for (int d0 = 0; d0 < C; d0 += 64) {
        #pragma unroll
        for (int q = 0; q < 8; ++q) {
            int rr = sr + q * 16;
            float4 v = *(const float4*)&Ab[(size_t)rr * C + d0 + scb];
            __bf16 h0 = (__bf16)v.x, h1 = (__bf16)v.y, h2 = (__bf16)v.z, h3 = (__bf16)v.w;
            bf16x4 hq = {h0, h1, h2, h3};
            bf16x4 lq = {(__bf16)(v.x - (float)h0), (__bf16)(v.y - (float)h1),
                         (__bf16)(v.z - (float)h2), (__bf16)(v.w - (float)h3)};
            int off = (rr * 128 + scb * 2) ^ ((rr & 7) << 4);
            *(bf16x4*)((char*)Ah + off) = hq;
            *(bf16x4*)((char*)Al + off) = lq;
        }
        __syncthreads();
        #pragma unroll
        for (int s = 0; s < 2; ++s) {
            const int k0 = s * 32 + lk;
            bf16x8 bv[2];
            #pragma unroll
            for (int tn = 0; tn < 2; ++tn) {
                const int w = quadw + tn * 16 + lr;
                bv[tn] = *(const bf16x8*)&Zhi[((size_t)b * P + h * 64 + w) * C + d0 + k0];
            }
            #pragma unroll
            for (int tm = 0; tm < 4; ++tm) {
                const int row = quadc + tm * 16 + lr;
                const int off = (row * 128 + k0 * 2) ^ ((row & 7) << 4);
                bf16x8 a_h = *(const bf16x8*)((char*)Ah + off);
                bf16x8 a_l = *(const bf16x8*)((char*)Al + off);
                #pragma unroll
                for (int tn = 0; tn < 2; ++tn) {
                    acc[tm][tn] = __builtin_amdgcn_mfma_f32_16x16x32_bf16(a_h, bv[tn], acc[tm][tn], 0, 0, 0);
                    acc[tm][tn] = __builtin_amdgcn_mfma_f32_16x16x32_bf16(a_l, bv[tn], acc[tm][tn], 0, 0, 0);
                }
            }
        }
        __syncthreads();
    }

    // store: lane holds col w (lane&15), 4 consecutive c rows -> float4 along c
    #pragma unroll
    for (int tm = 0; tm < 4; ++tm) {
        const int c0 = ct * 128 + quadc + tm * 16 + (lane >> 4) * 4;
        #pragma unroll
        for (int tn = 0; tn < 2; ++tn) {
            const int w = quadw + tn * 16 + lr;
            f32x4 v = acc[tm][tn];
            *(f32x4*)&out0[((size_t)b * P + h * 64 + w) * C + c0] = v;
        }
    }
}

extern "C" void kernel_launch(void* const* d_in, const int* in_sizes, int n_in,
                              void* d_out, int out_size, void* d_ws, size_t ws_size,
                              hipStream_t stream) {
    const float* x     = (const float*)d_in[0];
    const float* Wq    = (const float*)d_in[1];
    const float* gamma = (const float*)d_in[2];
    const float* beta  = (const float*)d_in[3];
    const float* mean  = (const float*)d_in[4];
    const float* var   = (const float*)d_in[5];
    const float* gs    = (const float*)d_in[6];

    float* out0 = (float*)d_out;                          // h: (B,P,C)
    float* attn = (float*)d_out + (size_t)B * P * C;      // attn: (B,H,C,C)

    const size_t NE = (size_t)B * C * P;                  // 4M elements
    __bf16* Yhi = (__bf16*)d_ws;                          // 8 MB
    __bf16* Ylo = Yhi + NE;                               // 8 MB
    __bf16* Zhi = Ylo + NE;                               // 8 MB

    qkv_bn_kernel<<<dim3(8, 8, 8), 256, 0, stream>>>(x, Wq, gamma, beta, mean, var,
                                                     Yhi, Ylo, Zhi);
    scores_softmax_mfma<<<dim3(16, 16, 8), 256, 0, stream>>>(Yhi, Ylo, gs, attn);
    pv_mfma<<<dim3(8, 64), 256, 0, stream>>>(attn, Zhi, out0);
}

// Round 4
// 400.441 us; speedup vs baseline: 1.9639x; 1.0737x over previous
//
#include <hip/hip_runtime.h>
#include <math.h>

#define B 8
#define P 512
#define C 1024
#define H 8
#define WD 64
#define BN_EPS 1e-5f

typedef __attribute__((ext_vector_type(8))) __bf16 bf16x8;
typedef __attribute__((ext_vector_type(4))) __bf16 bf16x4;
typedef __attribute__((ext_vector_type(4))) float f32x4;

// ---------------------------------------------------------------------------
// Kernel 0: split x (B,P,C) and W (C,C) into hi/lo bf16. One float4/thread.
// ---------------------------------------------------------------------------
__global__ __launch_bounds__(256) void split_hi_lo(
    const float* __restrict__ x, const float* __restrict__ Wq,
    __bf16* __restrict__ xhi, __bf16* __restrict__ xlo,
    __bf16* __restrict__ whi, __bf16* __restrict__ wlo)
{
    const size_t NX4 = (size_t)B * P * C / 4;      // 1048576 float4s of x
    size_t idx = (size_t)blockIdx.x * 256 + threadIdx.x;   // 0..1310719
    float4 v;
    __bf16 *dh, *dl;
    size_t o;
    if (idx < NX4) {
        v = ((const float4*)x)[idx];
        dh = xhi; dl = xlo; o = idx * 4;
    } else {
        v = ((const float4*)Wq)[idx - NX4];
        dh = whi; dl = wlo; o = (idx - NX4) * 4;
    }
    float f[4] = {v.x, v.y, v.z, v.w};
    bf16x4 hv, lv;
    #pragma unroll
    for (int j = 0; j < 4; ++j) {
        __bf16 hb = (__bf16)f[j];
        hv[j] = hb;
        lv[j] = (__bf16)(f[j] - (float)hb);
    }
    *(bf16x4*)&dh[o] = hv;
    *(bf16x4*)&dl[o] = lv;
}

// ---------------------------------------------------------------------------
// Kernel 1: Y[b,d,p] = BN( sum_c W[d,c] * x[b,p,c] ) via split-bf16 MFMA.
// Block (dt, pt, b): 64x64 tile, 4 waves x 32x32 quadrants. Fragments straight
// from global (no LDS, no syncs). Epilogue: BN + hi/lo split ->
//   Yhi/Ylo (B,C,P) for scores, Zhi (B,P,C) for pv — all direct from regs.
// ---------------------------------------------------------------------------
__global__ __launch_bounds__(256) void qkv_bn_mfma(
    const __bf16* __restrict__ xhi, const __bf16* __restrict__ xlo,
    const __bf16* __restrict__ whi, const __bf16* __restrict__ wlo,
    const float* __restrict__ gamma, const float* __restrict__ beta,
    const float* __restrict__ mean, const float* __restrict__ var,
    __bf16* __restrict__ Yhi, __bf16* __restrict__ Ylo, __bf16* __restrict__ Zhi)
{
    const int dt = blockIdx.x;   // 16
    const int pt = blockIdx.y;   // 8
    const int b  = blockIdx.z;   // 8
    const int t = threadIdx.x, lane = t & 63, wid = t >> 6;
    const int quadd = (wid >> 1) * 32, quadp = (wid & 1) * 32;
    const int lr = lane & 15, lk = (lane >> 4) * 8;

    const int drow0 = dt * 64 + quadd + lr;                         // A row, tm=0
    const size_t xrow0 = ((size_t)b * P + pt * 64 + quadp + lr) * C; // B row, tn=0

    f32x4 acc[2][2];
    #pragma unroll
    for (int tm = 0; tm < 2; ++tm)
        #pragma unroll
        for (int tn = 0; tn < 2; ++tn)
            acc[tm][tn] = (f32x4){0.f, 0.f, 0.f, 0.f};

    for (int c0 = 0; c0 < C; c0 += 32) {
        const int col = c0 + lk;
        bf16x8 ah[2], al[2], bh[2], bl[2];
        #pragma unroll
        for (int tm = 0; tm < 2; ++tm) {
            size_t ia = (size_t)(drow0 + tm * 16) * C + col;
            ah[tm] = *(const bf16x8*)&whi[ia];
            al[tm] = *(const bf16x8*)&wlo[ia];
        }
        #pragma unroll
        for (int tn = 0; tn < 2; ++tn) {
            size_t ib = xrow0 + (size_t)tn * 16 * C + col;
            bh[tn] = *(const bf16x8*)&xhi[ib];
            bl[tn] = *(const bf16x8*)&xlo[ib];
        }
        #pragma unroll
        for (int tm = 0; tm < 2; ++tm)
            #pragma unroll
            for (int tn = 0; tn < 2; ++tn) {
                acc[tm][tn] = __builtin_amdgcn_mfma_f32_16x16x32_bf16(ah[tm], bh[tn], acc[tm][tn], 0, 0, 0);
                acc[tm][tn] = __builtin_amdgcn_mfma_f32_16x16x32_bf16(ah[tm], bl[tn], acc[tm][tn], 0, 0, 0);
                acc[tm][tn] = __builtin_amdgcn_mfma_f32_16x16x32_bf16(al[tm], bh[tn], acc[tm][tn], 0, 0, 0);
            }
    }

    // epilogue: BN + hi/lo split, direct stores (acc: row d = base + r, col p = lr)
    const int rgrp = (lane >> 4) * 4;
    #pragma unroll
    for (int tm = 0; tm < 2; ++tm) {
        const int dbase = dt * 64 + quadd + tm * 16 + rgrp;
        float4 g4 = *(const float4*)&gamma[dbase];
        float4 bb4 = *(const float4*)&beta[dbase];
        float4 m4 = *(const float4*)&mean[dbase];
        float4 v4 = *(const float4*)&var[dbase];
        float gf[4] = {g4.x, g4.y, g4.z, g4.w};
        float bf[4] = {bb4.x, bb4.y, bb4.z, bb4.w};
        float mf[4] = {m4.x, m4.y, m4.z, m4.w};
        float vf[4] = {v4.x, v4.y, v4.z, v4.w};
        float sc[4];
        #pragma unroll
        for (int r = 0; r < 4; ++r) sc[r] = rsqrtf(vf[r] + BN_EPS) * gf[r];

        #pragma unroll
        for (int tn = 0; tn < 2; ++tn) {
            const int p = pt * 64 + quadp + tn * 16 + lr;
            bf16x4 zq;
            #pragma unroll
            for (int r = 0; r < 4; ++r) {
                float n = (acc[tm][tn][r] - mf[r]) * sc[r] + bf[r];
                __bf16 hb = (__bf16)n;
                __bf16 lb = (__bf16)(n - (float)hb);
                size_t yi = ((size_t)b * C + dbase + r) * P + p;
                Yhi[yi] = hb;
                Ylo[yi] = lb;
                zq[r] = hb;
            }
            *(bf16x4*)&Zhi[((size_t)b * P + p) * C + dbase] = zq;
        }
    }
}

// ---------------------------------------------------------------------------
// Kernel 2: scores + head-softmax via split-bf16 MFMA, fragments from global.
// Block (b, ct, dt): 4 waves, each a 32x32 quadrant x 8 heads. No LDS/syncs.
// ---------------------------------------------------------------------------
__global__ __launch_bounds__(256) void scores_softmax_mfma(
    const __bf16* __restrict__ Yhi, const __bf16* __restrict__ Ylo,
    const float* __restrict__ gs_ptr, float* __restrict__ attn)
{
    const int ct = blockIdx.x, dt = blockIdx.y, b = blockIdx.z;
    const int t = threadIdx.x, lane = t & 63, wid = t >> 6;
    const int quadc = (wid >> 1) * 32, quadd = (wid & 1) * 32;
    const int lr = lane & 15, lk = (lane >> 4) * 8;
    const float scale = 1.0f / gs_ptr[0];

    const size_t rowc = (size_t)b * C + ct * 64 + quadc + lr;
    const size_t rowd = (size_t)b * C + dt * 64 + quadd + lr;

    f32x4 acc[8][2][2];
    #pragma unroll
    for (int h = 0; h < H; ++h)
        #pragma unroll
        for (int tm = 0; tm < 2; ++tm)
            #pragma unroll
            for (int tn = 0; tn < 2; ++tn)
                acc[h][tm][tn] = (f32x4){0.f, 0.f, 0.f, 0.f};

    #pragma unroll
    for (int h = 0; h < H; ++h) {
        #pragma unroll
        for (int s = 0; s < 2; ++s) {
            const int col = h * 64 + s * 32 + lk;
            bf16x8 ah[2], al[2], bh[2], bl[2];
            #pragma unroll
            for (int tm = 0; tm < 2; ++tm) {
                size_t ia = (rowc + tm * 16) * P + col;
                ah[tm] = *(const bf16x8*)&Yhi[ia];
                al[tm] = *(const bf16x8*)&Ylo[ia];
                size_t ib = (rowd + tm * 16) * P + col;
                bh[tm] = *(const bf16x8*)&Yhi[ib];
                bl[tm] = *(const bf16x8*)&Ylo[ib];
            }
            #pragma unroll
            for (int tm = 0; tm < 2; ++tm)
                #pragma unroll
                for (int tn = 0; tn < 2; ++tn) {
                    acc[h][tm][tn] = __builtin_amdgcn_mfma_f32_16x16x32_bf16(ah[tm], bh[tn], acc[h][tm][tn], 0, 0, 0);
                    acc[h][tm][tn] = __builtin_amdgcn_mfma_f32_16x16x32_bf16(ah[tm], bl[tn], acc[h][tm][tn], 0, 0, 0);
                    acc[h][tm][tn] = __builtin_amdgcn_mfma_f32_16x16x32_bf16(al[tm], bh[tn], acc[h][tm][tn], 0, 0, 0);
                }
        }
    }

    #pragma unroll
    for (int tm = 0; tm < 2; ++tm)
        #pragma unroll
        for (int tn = 0; tn < 2; ++tn)
            #pragma unroll
            for (int r = 0; r < 4; ++r) {
                float v[8];
                float m = -1e30f;
                #pragma unroll
                for (int h = 0; h < H; ++h) {
                    v[h] = acc[h][tm][tn][r] * scale;
                    m = fmaxf(m, v[h]);
                }
                float ssum = 0.f;
                #pragma unroll
                for (int h = 0; h < H; ++h) { v[h] = __expf(v[h] - m); ssum += v[h]; }
                float inv = 1.0f / ssum;
                #pragma unroll
                for (int h = 0; h < H; ++h) acc[h][tm][tn][r] = v[h] * inv;
            }

    #pragma unroll
    for (int h = 0; h < H; ++h) {
        #pragma unroll
        for (int tm = 0; tm < 2; ++tm) {
            const int c = ct * 64 + quadc + tm * 16 + (lane >> 4) * 4;
            #pragma unroll
            for (int tn = 0; tn < 2; ++tn) {
                const int d = dt * 64 + quadd + tn * 16 + lr;
                float* op = attn + (((size_t)(b * H + h) * C + c) * C + d);
                #pragma unroll
                for (int r = 0; r < 4; ++r) op[(size_t)r * C] = acc[h][tm][tn][r];
            }
        }
    }
}

// ---------------------------------------------------------------------------
// Kernel 3: out0[b, h*64+w, c] = sum_d attn[b,h,c,d] * V[d,w]
// attn staged to LDS as hi/lo bf16 (XOR-swizzled rows); V frags from Zhi.
// ---------------------------------------------------------------------------
__global__ __launch_bounds__(256) void pv_mfma(
    const float* __restrict__ attn, const __bf16* __restrict__ Zhi,
    float* __restrict__ out0)
{
    const int ct = blockIdx.x;           // 8 tiles of 128 c
    const int bh = blockIdx.y;           // 64
    const int b = bh >> 3, h = bh & 7;
    const int t = threadIdx.x, lane = t & 63, wid = t >> 6;
    const int quadc = (wid >> 1) * 64;
    const int quadw = (wid & 1) * 32;
    const int lr = lane & 15, lk = (lane >> 4) * 8;

    __shared__ __bf16 Ah[128 * 64];
    __shared__ __bf16 Al[128 * 64];

    const float* Ab = attn + ((size_t)bh * C + (size_t)ct * 128) * C;

    f32x4 acc[4][2];
    #pragma unroll
    for (int tm = 0; tm < 4; ++tm)
        #pragma unroll
        for (int tn = 0; tn < 2; ++tn)
            acc[tm][tn] = (f32x4){0.f, 0.f, 0.f, 0.f};

    const int sr  = t >> 4;
    const int scb = (t & 15) * 4;

    for (int d0 = 0; d0 < C; d0 += 64) {
        #pragma unroll
        for (int q = 0; q < 8; ++q) {
            int rr = sr + q * 16;
            float4 v = *(const float4*)&Ab[(size_t)rr * C + d0 + scb];
            __bf16 h0 = (__bf16)v.x, h1 = (__bf16)v.y, h2 = (__bf16)v.z, h3 = (__bf16)v.w;
            bf16x4 hq = {h0, h1, h2, h3};
            bf16x4 lq = {(__bf16)(v.x - (float)h0), (__bf16)(v.y - (float)h1),
                         (__bf16)(v.z - (float)h2), (__bf16)(v.w - (float)h3)};
            int off = (rr * 128 + scb * 2) ^ ((rr & 7) << 4);
            *(bf16x4*)((char*)Ah + off) = hq;
            *(bf16x4*)((char*)Al + off) = lq;
        }
        __syncthreads();
        #pragma unroll
        for (int s = 0; s < 2; ++s) {
            const int k0 = s * 32 + lk;
            bf16x8 bv[2];
            #pragma unroll
            for (int tn = 0; tn < 2; ++tn) {
                const int w = quadw + tn * 16 + lr;
                bv[tn] = *(const bf16x8*)&Zhi[((size_t)b * P + h * 64 + w) * C + d0 + k0];
            }
            #pragma unroll
            for (int tm = 0; tm < 4; ++tm) {
                const int row = quadc + tm * 16 + lr;
                const int off = (row * 128 + k0 * 2) ^ ((row & 7) << 4);
                bf16x8 a_h = *(const bf16x8*)((char*)Ah + off);
                bf16x8 a_l = *(const bf16x8*)((char*)Al + off);
                #pragma unroll
                for (int tn = 0; tn < 2; ++tn) {
                    acc[tm][tn] = __builtin_amdgcn_mfma_f32_16x16x32_bf16(a_h, bv[tn], acc[tm][tn], 0, 0, 0);
                    acc[tm][tn] = __builtin_amdgcn_mfma_f32_16x16x32_bf16(a_l, bv[tn], acc[tm][tn], 0, 0, 0);
                }
            }
        }
        __syncthreads();
    }

    #pragma unroll
    for (int tm = 0; tm < 4; ++tm) {
        const int c0 = ct * 128 + quadc + tm * 16 + (lane >> 4) * 4;
        #pragma unroll
        for (int tn = 0; tn < 2; ++tn) {
            const int w = quadw + tn * 16 + lr;
            f32x4 v = acc[tm][tn];
            *(f32x4*)&out0[((size_t)b * P + h * 64 + w) * C + c0] = v;
        }
    }
}

extern "C" void kernel_launch(void* const* d_in, const int* in_sizes, int n_in,
                              void* d_out, int out_size, void* d_ws, size_t ws_size,
                              hipStream_t stream) {
    const float* x     = (const float*)d_in[0];
    const float* Wq    = (const float*)d_in[1];
    const float* gamma = (const float*)d_in[2];
    const float* beta  = (const float*)d_in[3];
    const float* mean  = (const float*)d_in[4];
    const float* var   = (const float*)d_in[5];
    const float* gs    = (const float*)d_in[6];

    float* out0 = (float*)d_out;                          // h: (B,P,C), 4M f32
    float* attn = (float*)d_out + (size_t)B * P * C;      // attn: (B,H,C,C), 64M f32

    const size_t NE = (size_t)B * C * P;                  // 4M elements
    __bf16* Yhi = (__bf16*)d_ws;                          // 8 MB
    __bf16* Ylo = Yhi + NE;                               // 8 MB
    __bf16* Zhi = Ylo + NE;                               // 8 MB

    // transient scratch in the attn-region tail (dead before scores writes it):
    // xhi/xlo: 4M bf16 each, whi/wlo: 1M bf16 each = 10M bf16 = 5M f32 slots
    const size_t attn_elems = (size_t)B * H * C * C;      // 67108864
    __bf16* S = (__bf16*)(attn + (attn_elems - 5242880));
    __bf16* xhi = S;
    __bf16* xlo = xhi + (size_t)B * P * C;
    __bf16* whi = xlo + (size_t)B * P * C;
    __bf16* wlo = whi + (size_t)C * C;

    split_hi_lo<<<5120, 256, 0, stream>>>(x, Wq, xhi, xlo, whi, wlo);
    qkv_bn_mfma<<<dim3(16, 8, 8), 256, 0, stream>>>(xhi, xlo, whi, wlo,
                                                    gamma, beta, mean, var,
                                                    Yhi, Ylo, Zhi);
    scores_softmax_mfma<<<dim3(16, 16, 8), 256, 0, stream>>>(Yhi, Ylo, gs, attn);
    pv_mfma<<<dim3(8, 64), 256, 0, stream>>>(attn, Zhi, out0);
}

// Round 5
// 385.997 us; speedup vs baseline: 2.0374x; 1.0374x over previous
//
#include <hip/hip_runtime.h>
#include <math.h>

#define B 8
#define P 512
#define C 1024
#define H 8
#define BN_EPS 1e-5f

typedef __attribute__((ext_vector_type(8))) __bf16 bf16x8;
typedef __attribute__((ext_vector_type(4))) __bf16 bf16x4;
typedef __attribute__((ext_vector_type(4))) float f32x4;

// ---------------------------------------------------------------------------
// Kernel 0: split x (B,P,C) and W (C,C) into hi/lo bf16. One float4/thread.
// ---------------------------------------------------------------------------
__global__ __launch_bounds__(256) void split_hi_lo(
    const float* __restrict__ x, const float* __restrict__ Wq,
    __bf16* __restrict__ xhi, __bf16* __restrict__ xlo,
    __bf16* __restrict__ whi, __bf16* __restrict__ wlo)
{
    const size_t NX4 = (size_t)B * P * C / 4;
    size_t idx = (size_t)blockIdx.x * 256 + threadIdx.x;
    float4 v;
    __bf16 *dh, *dl;
    size_t o;
    if (idx < NX4) {
        v = ((const float4*)x)[idx];
        dh = xhi; dl = xlo; o = idx * 4;
    } else {
        v = ((const float4*)Wq)[idx - NX4];
        dh = whi; dl = wlo; o = (idx - NX4) * 4;
    }
    float f[4] = {v.x, v.y, v.z, v.w};
    bf16x4 hv, lv;
    #pragma unroll
    for (int j = 0; j < 4; ++j) {
        __bf16 hb = (__bf16)f[j];
        hv[j] = hb;
        lv[j] = (__bf16)(f[j] - (float)hb);
    }
    *(bf16x4*)&dh[o] = hv;
    *(bf16x4*)&dl[o] = lv;
}

// ---------------------------------------------------------------------------
// Kernel 1: Y[b,d,p] = BN( sum_c W[d,c] * x[b,p,c] ) via split-bf16 MFMA.
// (unchanged from round 4 — proven)
// ---------------------------------------------------------------------------
__global__ __launch_bounds__(256) void qkv_bn_mfma(
    const __bf16* __restrict__ xhi, const __bf16* __restrict__ xlo,
    const __bf16* __restrict__ whi, const __bf16* __restrict__ wlo,
    const float* __restrict__ gamma, const float* __restrict__ beta,
    const float* __restrict__ mean, const float* __restrict__ var,
    __bf16* __restrict__ Yhi, __bf16* __restrict__ Ylo, __bf16* __restrict__ Zhi)
{
    const int dt = blockIdx.x;   // 16
    const int pt = blockIdx.y;   // 8
    const int b  = blockIdx.z;   // 8
    const int t = threadIdx.x, lane = t & 63, wid = t >> 6;
    const int quadd = (wid >> 1) * 32, quadp = (wid & 1) * 32;
    const int lr = lane & 15, lk = (lane >> 4) * 8;

    const int drow0 = dt * 64 + quadd + lr;
    const size_t xrow0 = ((size_t)b * P + pt * 64 + quadp + lr) * C;

    f32x4 acc[2][2];
    #pragma unroll
    for (int tm = 0; tm < 2; ++tm)
        #pragma unroll
        for (int tn = 0; tn < 2; ++tn)
            acc[tm][tn] = (f32x4){0.f, 0.f, 0.f, 0.f};

    for (int c0 = 0; c0 < C; c0 += 32) {
        const int col = c0 + lk;
        bf16x8 ah[2], al[2], bh[2], bl[2];
        #pragma unroll
        for (int tm = 0; tm < 2; ++tm) {
            size_t ia = (size_t)(drow0 + tm * 16) * C + col;
            ah[tm] = *(const bf16x8*)&whi[ia];
            al[tm] = *(const bf16x8*)&wlo[ia];
        }
        #pragma unroll
        for (int tn = 0; tn < 2; ++tn) {
            size_t ib = xrow0 + (size_t)tn * 16 * C + col;
            bh[tn] = *(const bf16x8*)&xhi[ib];
            bl[tn] = *(const bf16x8*)&xlo[ib];
        }
        #pragma unroll
        for (int tm = 0; tm < 2; ++tm)
            #pragma unroll
            for (int tn = 0; tn < 2; ++tn) {
                acc[tm][tn] = __builtin_amdgcn_mfma_f32_16x16x32_bf16(ah[tm], bh[tn], acc[tm][tn], 0, 0, 0);
                acc[tm][tn] = __builtin_amdgcn_mfma_f32_16x16x32_bf16(ah[tm], bl[tn], acc[tm][tn], 0, 0, 0);
                acc[tm][tn] = __builtin_amdgcn_mfma_f32_16x16x32_bf16(al[tm], bh[tn], acc[tm][tn], 0, 0, 0);
            }
    }

    const int rgrp = (lane >> 4) * 4;
    #pragma unroll
    for (int tm = 0; tm < 2; ++tm) {
        const int dbase = dt * 64 + quadd + tm * 16 + rgrp;
        float4 g4 = *(const float4*)&gamma[dbase];
        float4 bb4 = *(const float4*)&beta[dbase];
        float4 m4 = *(const float4*)&mean[dbase];
        float4 v4 = *(const float4*)&var[dbase];
        float gf[4] = {g4.x, g4.y, g4.z, g4.w};
        float bf[4] = {bb4.x, bb4.y, bb4.z, bb4.w};
        float mf[4] = {m4.x, m4.y, m4.z, m4.w};
        float vf[4] = {v4.x, v4.y, v4.z, v4.w};
        float sc[4];
        #pragma unroll
        for (int r = 0; r < 4; ++r) sc[r] = rsqrtf(vf[r] + BN_EPS) * gf[r];

        #pragma unroll
        for (int tn = 0; tn < 2; ++tn) {
            const int p = pt * 64 + quadp + tn * 16 + lr;
            bf16x4 zq;
            #pragma unroll
            for (int r = 0; r < 4; ++r) {
                float n = (acc[tm][tn][r] - mf[r]) * sc[r] + bf[r];
                __bf16 hb = (__bf16)n;
                __bf16 lb = (__bf16)(n - (float)hb);
                size_t yi = ((size_t)b * C + dbase + r) * P + p;
                Yhi[yi] = hb;
                Ylo[yi] = lb;
                zq[r] = hb;
            }
            *(bf16x4*)&Zhi[((size_t)b * P + p) * C + dbase] = zq;
        }
    }
}

// ---------------------------------------------------------------------------
// Kernel 2 (FUSED): scores + head-softmax + attn-write + PV, one pass over d.
// Softmax axis (h) is local to each (c,d) -> no cross-chunk state.
// Block: (ct: 32 c, b). 512 threads = 8 waves.
//   scores roles: (si = w&1: c-half, sq = w>>1: d-quarter of 64)
//   pv roles:     (pi = w&1: c-half, pj: w-half, pk: d-half)
// Per d-chunk(64): MFMA scores (3-product split), softmax over h in-register,
// write attn f32 (only touch of HBM for attn), P->bf16 in LDS, PV MFMA (hi-only).
// ---------------------------------------------------------------------------
__global__ __launch_bounds__(512) void attn_fused(
    const __bf16* __restrict__ Yhi, const __bf16* __restrict__ Ylo,
    const __bf16* __restrict__ Zhi, const float* __restrict__ gs_ptr,
    float* __restrict__ attn, float* __restrict__ out0)
{
    const int ct = blockIdx.x;        // 32 tiles of 32 c
    const int b  = blockIdx.y;        // 8
    const int c0 = ct * 32;
    const int t = threadIdx.x, lane = t & 63, w = t >> 6;
    const int lr = lane & 15, lk = (lane >> 4) * 8, rgrp = (lane >> 4) * 4;
    const int si = w & 1;             // scores c-half
    const int sq = w >> 1;            // scores d-quarter (0..3)
    const int pi = w & 1;             // pv c-half
    const int pj = (w >> 1) & 1;      // pv w-half
    const int pk = w >> 2;            // pv d-half
    const float scale = 1.0f / gs_ptr[0];

    __shared__ __align__(16) char smem[65536];
    __bf16 (*Plds)[32][72] = (__bf16(*)[32][72])smem;   // [h][c32][d64 pad72] = 36 KB
    float* Cmb = (float*)smem;                          // 4 x 16 KB regions = 64 KB
    float (*Olds)[36] = (float(*)[36])smem;             // [w64][c32 pad36] = 9 KB

    f32x4 out_acc[8][2];
    #pragma unroll
    for (int h = 0; h < H; ++h) {
        out_acc[h][0] = (f32x4){0.f, 0.f, 0.f, 0.f};
        out_acc[h][1] = (f32x4){0.f, 0.f, 0.f, 0.f};
    }

    const int crow = c0 + si * 16 + lr;
    const size_t YbaseC = ((size_t)b * C + crow) * P;

    for (int dbase = 0; dbase < C; dbase += 64) {
        // ---- phase 1: scores quadrant (16c x 16d) for all 8 heads ----
        const int drow = dbase + sq * 16 + lr;
        const size_t YbaseD = ((size_t)b * C + drow) * P;

        f32x4 sacc[8];
        #pragma unroll
        for (int h = 0; h < H; ++h) sacc[h] = (f32x4){0.f, 0.f, 0.f, 0.f};

        #pragma unroll
        for (int h = 0; h < H; ++h) {
            #pragma unroll
            for (int s = 0; s < 2; ++s) {
                const int col = h * 64 + s * 32 + lk;
                bf16x8 ah = *(const bf16x8*)&Yhi[YbaseC + col];
                bf16x8 al = *(const bf16x8*)&Ylo[YbaseC + col];
                bf16x8 bh = *(const bf16x8*)&Yhi[YbaseD + col];
                bf16x8 bl = *(const bf16x8*)&Ylo[YbaseD + col];
                sacc[h] = __builtin_amdgcn_mfma_f32_16x16x32_bf16(ah, bh, sacc[h], 0, 0, 0);
                sacc[h] = __builtin_amdgcn_mfma_f32_16x16x32_bf16(ah, bl, sacc[h], 0, 0, 0);
                sacc[h] = __builtin_amdgcn_mfma_f32_16x16x32_bf16(al, bh, sacc[h], 0, 0, 0);
            }
        }

        // ---- softmax over h per (c,d); write attn f32 + P bf16 to LDS ----
        const int dcol = dbase + sq * 16 + lr;
        #pragma unroll
        for (int r = 0; r < 4; ++r) {
            const int c = c0 + si * 16 + rgrp + r;
            float v[8];
            float m = -1e30f;
            #pragma unroll
            for (int h = 0; h < H; ++h) {
                v[h] = sacc[h][r] * scale;
                m = fmaxf(m, v[h]);
            }
            float ssum = 0.f;
            #pragma unroll
            for (int h = 0; h < H; ++h) { v[h] = __expf(v[h] - m); ssum += v[h]; }
            float inv = 1.0f / ssum;
            #pragma unroll
            for (int h = 0; h < H; ++h) {
                float p = v[h] * inv;
                attn[(((size_t)(b * H + h) * C + c) * C) + dcol] = p;
                Plds[h][si * 16 + rgrp + r][sq * 16 + lr] = (__bf16)p;
            }
        }
        __syncthreads();

        // ---- phase 2: PV partial for this d-chunk (hi-only) ----
        #pragma unroll
        for (int h = 0; h < H; ++h) {
            bf16x8 a = *(const bf16x8*)&Plds[h][pi * 16 + lr][pk * 32 + lk];
            #pragma unroll
            for (int tn = 0; tn < 2; ++tn) {
                const int p = h * 64 + pj * 32 + tn * 16 + lr;
                bf16x8 bv = *(const bf16x8*)&Zhi[((size_t)b * P + p) * C + dbase + pk * 32 + lk];
                out_acc[h][tn] = __builtin_amdgcn_mfma_f32_16x16x32_bf16(a, bv, out_acc[h][tn], 0, 0, 0);
            }
        }
        __syncthreads();
    }

    // ---- combine d-halves across pk via LDS ----
    if (pk == 1) {
        float* reg = Cmb + (size_t)(w - 4) * 4096;
        #pragma unroll
        for (int h = 0; h < H; ++h)
            #pragma unroll
            for (int tn = 0; tn < 2; ++tn)
                #pragma unroll
                for (int r = 0; r < 4; ++r)
                    reg[((h * 2 + tn) * 4 + r) * 64 + lane] = out_acc[h][tn][r];
    }
    __syncthreads();
    if (pk == 0) {
        const float* reg = Cmb + (size_t)w * 4096;
        #pragma unroll
        for (int h = 0; h < H; ++h)
            #pragma unroll
            for (int tn = 0; tn < 2; ++tn)
                #pragma unroll
                for (int r = 0; r < 4; ++r)
                    out_acc[h][tn][r] += reg[((h * 2 + tn) * 4 + r) * 64 + lane];
    }
    __syncthreads();

    // ---- epilogue: per head, LDS-transpose then coalesced out0 store ----
    #pragma unroll
    for (int h = 0; h < H; ++h) {
        if (pk == 0) {
            #pragma unroll
            for (int tn = 0; tn < 2; ++tn)
                #pragma unroll
                for (int r = 0; r < 4; ++r)
                    Olds[pj * 32 + tn * 16 + lr][pi * 16 + rgrp + r] = out_acc[h][tn][r];
        }
        __syncthreads();
        {
            const int row = t >> 3;            // 0..63 (w within head)
            const int coff = (t & 7) * 4;      // 0..28
            f32x4 vv = *(const f32x4*)&Olds[row][coff];
            *(f32x4*)&out0[((size_t)b * P + h * 64 + row) * C + c0 + coff] = vv;
        }
        __syncthreads();
    }
}

extern "C" void kernel_launch(void* const* d_in, const int* in_sizes, int n_in,
                              void* d_out, int out_size, void* d_ws, size_t ws_size,
                              hipStream_t stream) {
    const float* x     = (const float*)d_in[0];
    const float* Wq    = (const float*)d_in[1];
    const float* gamma = (const float*)d_in[2];
    const float* beta  = (const float*)d_in[3];
    const float* mean  = (const float*)d_in[4];
    const float* var   = (const float*)d_in[5];
    const float* gs    = (const float*)d_in[6];

    float* out0 = (float*)d_out;                          // h: (B,P,C)
    float* attn = (float*)d_out + (size_t)B * P * C;      // attn: (B,H,C,C)

    const size_t NE = (size_t)B * C * P;                  // 4M elements
    __bf16* Yhi = (__bf16*)d_ws;                          // 8 MB
    __bf16* Ylo = Yhi + NE;                               // 8 MB
    __bf16* Zhi = Ylo + NE;                               // 8 MB

    // transient scratch in the attn-region tail (dead before attn is written)
    const size_t attn_elems = (size_t)B * H * C * C;
    __bf16* S = (__bf16*)(attn + (attn_elems - 5242880));
    __bf16* xhi = S;
    __bf16* xlo = xhi + (size_t)B * P * C;
    __bf16* whi = xlo + (size_t)B * P * C;
    __bf16* wlo = whi + (size_t)C * C;

    split_hi_lo<<<5120, 256, 0, stream>>>(x, Wq, xhi, xlo, whi, wlo);
    qkv_bn_mfma<<<dim3(16, 8, 8), 256, 0, stream>>>(xhi, xlo, whi, wlo,
                                                    gamma, beta, mean, var,
                                                    Yhi, Ylo, Zhi);
    attn_fused<<<dim3(32, 8), 512, 0, stream>>>(Yhi, Ylo, Zhi, gs, attn, out0);
}

// Round 6
// 331.938 us; speedup vs baseline: 2.3692x; 1.1629x over previous
//
#include <hip/hip_runtime.h>
#include <math.h>

#define B 8
#define P 512
#define C 1024
#define H 8
#define BN_EPS 1e-5f

typedef __attribute__((ext_vector_type(8))) __bf16 bf16x8;
typedef __attribute__((ext_vector_type(4))) __bf16 bf16x4;
typedef __attribute__((ext_vector_type(4))) float f32x4;

// ---------------------------------------------------------------------------
// Kernel 0: split x (B,P,C) and W (C,C) into hi/lo bf16. One float4/thread.
// ---------------------------------------------------------------------------
__global__ __launch_bounds__(256) void split_hi_lo(
    const float* __restrict__ x, const float* __restrict__ Wq,
    __bf16* __restrict__ xhi, __bf16* __restrict__ xlo,
    __bf16* __restrict__ whi, __bf16* __restrict__ wlo)
{
    const size_t NX4 = (size_t)B * P * C / 4;
    size_t idx = (size_t)blockIdx.x * 256 + threadIdx.x;
    float4 v;
    __bf16 *dh, *dl;
    size_t o;
    if (idx < NX4) {
        v = ((const float4*)x)[idx];
        dh = xhi; dl = xlo; o = idx * 4;
    } else {
        v = ((const float4*)Wq)[idx - NX4];
        dh = whi; dl = wlo; o = (idx - NX4) * 4;
    }
    float f[4] = {v.x, v.y, v.z, v.w};
    bf16x4 hv, lv;
    #pragma unroll
    for (int j = 0; j < 4; ++j) {
        __bf16 hb = (__bf16)f[j];
        hv[j] = hb;
        lv[j] = (__bf16)(f[j] - (float)hb);
    }
    *(bf16x4*)&dh[o] = hv;
    *(bf16x4*)&dl[o] = lv;
}

// ---------------------------------------------------------------------------
// Kernel 1: Y[b,d,p] = BN( sum_c W[d,c] * x[b,p,c] ) via split-bf16 MFMA.
// (unchanged — proven)
// ---------------------------------------------------------------------------
__global__ __launch_bounds__(256) void qkv_bn_mfma(
    const __bf16* __restrict__ xhi, const __bf16* __restrict__ xlo,
    const __bf16* __restrict__ whi, const __bf16* __restrict__ wlo,
    const float* __restrict__ gamma, const float* __restrict__ beta,
    const float* __restrict__ mean, const float* __restrict__ var,
    __bf16* __restrict__ Yhi, __bf16* __restrict__ Ylo, __bf16* __restrict__ Zhi)
{
    const int dt = blockIdx.x;   // 16
    const int pt = blockIdx.y;   // 8
    const int b  = blockIdx.z;   // 8
    const int t = threadIdx.x, lane = t & 63, wid = t >> 6;
    const int quadd = (wid >> 1) * 32, quadp = (wid & 1) * 32;
    const int lr = lane & 15, lk = (lane >> 4) * 8;

    const int drow0 = dt * 64 + quadd + lr;
    const size_t xrow0 = ((size_t)b * P + pt * 64 + quadp + lr) * C;

    f32x4 acc[2][2];
    #pragma unroll
    for (int tm = 0; tm < 2; ++tm)
        #pragma unroll
        for (int tn = 0; tn < 2; ++tn)
            acc[tm][tn] = (f32x4){0.f, 0.f, 0.f, 0.f};

    for (int c0 = 0; c0 < C; c0 += 32) {
        const int col = c0 + lk;
        bf16x8 ah[2], al[2], bh[2], bl[2];
        #pragma unroll
        for (int tm = 0; tm < 2; ++tm) {
            size_t ia = (size_t)(drow0 + tm * 16) * C + col;
            ah[tm] = *(const bf16x8*)&whi[ia];
            al[tm] = *(const bf16x8*)&wlo[ia];
        }
        #pragma unroll
        for (int tn = 0; tn < 2; ++tn) {
            size_t ib = xrow0 + (size_t)tn * 16 * C + col;
            bh[tn] = *(const bf16x8*)&xhi[ib];
            bl[tn] = *(const bf16x8*)&xlo[ib];
        }
        #pragma unroll
        for (int tm = 0; tm < 2; ++tm)
            #pragma unroll
            for (int tn = 0; tn < 2; ++tn) {
                acc[tm][tn] = __builtin_amdgcn_mfma_f32_16x16x32_bf16(ah[tm], bh[tn], acc[tm][tn], 0, 0, 0);
                acc[tm][tn] = __builtin_amdgcn_mfma_f32_16x16x32_bf16(ah[tm], bl[tn], acc[tm][tn], 0, 0, 0);
                acc[tm][tn] = __builtin_amdgcn_mfma_f32_16x16x32_bf16(al[tm], bh[tn], acc[tm][tn], 0, 0, 0);
            }
    }

    const int rgrp = (lane >> 4) * 4;
    #pragma unroll
    for (int tm = 0; tm < 2; ++tm) {
        const int dbase = dt * 64 + quadd + tm * 16 + rgrp;
        float4 g4 = *(const float4*)&gamma[dbase];
        float4 bb4 = *(const float4*)&beta[dbase];
        float4 m4 = *(const float4*)&mean[dbase];
        float4 v4 = *(const float4*)&var[dbase];
        float gf[4] = {g4.x, g4.y, g4.z, g4.w};
        float bf[4] = {bb4.x, bb4.y, bb4.z, bb4.w};
        float mf[4] = {m4.x, m4.y, m4.z, m4.w};
        float vf[4] = {v4.x, v4.y, v4.z, v4.w};
        float sc[4];
        #pragma unroll
        for (int r = 0; r < 4; ++r) sc[r] = rsqrtf(vf[r] + BN_EPS) * gf[r];

        #pragma unroll
        for (int tn = 0; tn < 2; ++tn) {
            const int p = pt * 64 + quadp + tn * 16 + lr;
            bf16x4 zq;
            #pragma unroll
            for (int r = 0; r < 4; ++r) {
                float n = (acc[tm][tn][r] - mf[r]) * sc[r] + bf[r];
                __bf16 hb = (__bf16)n;
                __bf16 lb = (__bf16)(n - (float)hb);
                size_t yi = ((size_t)b * C + dbase + r) * P + p;
                Yhi[yi] = hb;
                Ylo[yi] = lb;
                zq[r] = hb;
            }
            *(bf16x4*)&Zhi[((size_t)b * P + p) * C + dbase] = zq;
        }
    }
}

// ---------------------------------------------------------------------------
// Kernel 2 (FUSED v2): scores + head-softmax + attn-write + PV.
// Grid 512 1-D: b = id&7 (XCD-pinned: one batch's Yhi/Ylo/Zhi = 3 MB fits an
// XCD L2), ct = id>>3 (64 tiles of 16 c). 256 threads = 4 waves.
// Wave roles: scores -> d-quarter (w*16); PV -> p-quarter per head (w*16).
// A-side hi fragments hoisted to registers (reused by all 16 d-chunks);
// PV Zhi loads issued before the barrier to overlap.
// ---------------------------------------------------------------------------
__global__ __launch_bounds__(256, 2) void attn_fused(
    const __bf16* __restrict__ Yhi, const __bf16* __restrict__ Ylo,
    const __bf16* __restrict__ Zhi, const float* __restrict__ gs_ptr,
    float* __restrict__ attn, float* __restrict__ out0)
{
    const int id = blockIdx.x;
    const int b  = id & 7;            // XCD pin
    const int ct = id >> 3;           // 0..63
    const int c0 = ct * 16;
    const int t = threadIdx.x, lane = t & 63, w = t >> 6;
    const int lr = lane & 15, lk = (lane >> 4) * 8, rgrp = (lane >> 4) * 4;
    const float scale = 1.0f / gs_ptr[0];

    __shared__ __bf16 Plds[8][16][72];   // [h][c16][d64 pad] = 18 KB
    __shared__ float Olds[64][20];       // transpose buffer = 5 KB

    // hoist A-side hi fragments: row c0+lr, cols h*64+s*32+lk (+0..7)
    const size_t YbaseC = ((size_t)b * C + c0 + lr) * P;
    bf16x8 ah[16];
    #pragma unroll
    for (int h = 0; h < H; ++h)
        #pragma unroll
        for (int s = 0; s < 2; ++s)
            ah[h * 2 + s] = *(const bf16x8*)&Yhi[YbaseC + h * 64 + s * 32 + lk];

    f32x4 out_acc[8];
    #pragma unroll
    for (int h = 0; h < H; ++h) out_acc[h] = (f32x4){0.f, 0.f, 0.f, 0.f};

    for (int dbase = 0; dbase < C; dbase += 64) {
        // ---- phase 1: scores 16c x 16d (this wave's d-quarter), all 8 heads
        const int drow = dbase + w * 16 + lr;
        const size_t YbaseD = ((size_t)b * C + drow) * P;

        f32x4 sacc[8];
        #pragma unroll
        for (int h = 0; h < H; ++h) sacc[h] = (f32x4){0.f, 0.f, 0.f, 0.f};

        #pragma unroll
        for (int h = 0; h < H; ++h) {
            #pragma unroll
            for (int s = 0; s < 2; ++s) {
                const int col = h * 64 + s * 32 + lk;
                bf16x8 bh = *(const bf16x8*)&Yhi[YbaseD + col];
                bf16x8 bl = *(const bf16x8*)&Ylo[YbaseD + col];
                bf16x8 av = *(const bf16x8*)&Ylo[YbaseC + col];
                sacc[h] = __builtin_amdgcn_mfma_f32_16x16x32_bf16(ah[h * 2 + s], bh, sacc[h], 0, 0, 0);
                sacc[h] = __builtin_amdgcn_mfma_f32_16x16x32_bf16(ah[h * 2 + s], bl, sacc[h], 0, 0, 0);
                sacc[h] = __builtin_amdgcn_mfma_f32_16x16x32_bf16(av, bh, sacc[h], 0, 0, 0);
            }
        }

        // ---- softmax over h per (c,d); write attn + P(bf16) to LDS ----
        const int dcol = dbase + w * 16 + lr;
        #pragma unroll
        for (int r = 0; r < 4; ++r) {
            const int c = c0 + rgrp + r;
            float v[8];
            float m = -1e30f;
            #pragma unroll
            for (int h = 0; h < H; ++h) {
                v[h] = sacc[h][r] * scale;
                m = fmaxf(m, v[h]);
            }
            float ssum = 0.f;
            #pragma unroll
            for (int h = 0; h < H; ++h) { v[h] = __expf(v[h] - m); ssum += v[h]; }
            float inv = 1.0f / ssum;
            #pragma unroll
            for (int h = 0; h < H; ++h) {
                float p = v[h] * inv;
                attn[(((size_t)(b * H + h) * C + c) * C) + dcol] = p;
                Plds[h][rgrp + r][w * 16 + lr] = (__bf16)p;
            }
        }

        // ---- issue PV B-side loads before the barrier (overlap) ----
        bf16x8 bv[8][2];
        #pragma unroll
        for (int h = 0; h < H; ++h) {
            const int p = h * 64 + w * 16 + lr;
            #pragma unroll
            for (int kh = 0; kh < 2; ++kh)
                bv[h][kh] = *(const bf16x8*)&Zhi[((size_t)b * P + p) * C + dbase + kh * 32 + lk];
        }
        __syncthreads();

        // ---- phase 2: PV partial (hi-only P, hi-only V) ----
        #pragma unroll
        for (int h = 0; h < H; ++h) {
            #pragma unroll
            for (int kh = 0; kh < 2; ++kh) {
                bf16x8 a = *(const bf16x8*)&Plds[h][lr][kh * 32 + lk];
                out_acc[h] = __builtin_amdgcn_mfma_f32_16x16x32_bf16(a, bv[h][kh], out_acc[h], 0, 0, 0);
            }
        }
        __syncthreads();
    }

    // ---- epilogue: per head, LDS transpose then coalesced out0 store ----
    #pragma unroll
    for (int h = 0; h < H; ++h) {
        #pragma unroll
        for (int r = 0; r < 4; ++r)
            Olds[w * 16 + lr][rgrp + r] = out_acc[h][r];
        __syncthreads();
        {
            const int row = t >> 2;            // 0..63 (p within head)
            const int coff = (t & 3) * 4;      // 0..12
            f32x4 vv = *(const f32x4*)&Olds[row][coff];
            *(f32x4*)&out0[((size_t)b * P + h * 64 + row) * C + c0 + coff] = vv;
        }
        __syncthreads();
    }
}

extern "C" void kernel_launch(void* const* d_in, const int* in_sizes, int n_in,
                              void* d_out, int out_size, void* d_ws, size_t ws_size,
                              hipStream_t stream) {
    const float* x     = (const float*)d_in[0];
    const float* Wq    = (const float*)d_in[1];
    const float* gamma = (const float*)d_in[2];
    const float* beta  = (const float*)d_in[3];
    const float* mean  = (const float*)d_in[4];
    const float* var   = (const float*)d_in[5];
    const float* gs    = (const float*)d_in[6];

    float* out0 = (float*)d_out;                          // h: (B,P,C)
    float* attn = (float*)d_out + (size_t)B * P * C;      // attn: (B,H,C,C)

    const size_t NE = (size_t)B * C * P;                  // 4M elements
    __bf16* Yhi = (__bf16*)d_ws;                          // 8 MB
    __bf16* Ylo = Yhi + NE;                               // 8 MB
    __bf16* Zhi = Ylo + NE;                               // 8 MB

    // transient scratch in the attn-region tail (dead before attn is written)
    const size_t attn_elems = (size_t)B * H * C * C;
    __bf16* S = (__bf16*)(attn + (attn_elems - 5242880));
    __bf16* xhi = S;
    __bf16* xlo = xhi + (size_t)B * P * C;
    __bf16* whi = xlo + (size_t)B * P * C;
    __bf16* wlo = whi + (size_t)C * C;

    split_hi_lo<<<5120, 256, 0, stream>>>(x, Wq, xhi, xlo, whi, wlo);
    qkv_bn_mfma<<<dim3(16, 8, 8), 256, 0, stream>>>(xhi, xlo, whi, wlo,
                                                    gamma, beta, mean, var,
                                                    Yhi, Ylo, Zhi);
    attn_fused<<<512, 256, 0, stream>>>(Yhi, Ylo, Zhi, gs, attn, out0);
}